// Round 4
// baseline (457.524 us; speedup 1.0000x reference)
//
#include <hip/hip_runtime.h>
#include <hip/hip_bf16.h>

// MEASUREMENT ROUND: kernels byte-identical to R3; attn dispatched 8x to
// attribute per-kernel time from total dur:  attn = (T4-T3)/7.
// All kernels are idempotent so duplicate dispatches are capture-safe.

typedef float  f32x4  __attribute__((ext_vector_type(4)));
typedef float  f32x16 __attribute__((ext_vector_type(16)));
typedef short  s16x8  __attribute__((ext_vector_type(8)));
typedef short  s16x4  __attribute__((ext_vector_type(4)));

#define MFMA16(A, B, C) __builtin_amdgcn_mfma_f32_16x16x32_bf16((A), (B), (C), 0, 0, 0)
#define MFMA32(A, B, C) __builtin_amdgcn_mfma_f32_32x32x16_bf16((A), (B), (C), 0, 0, 0)

static __device__ __forceinline__ ushort f2bf(float f) {
    union { float f; unsigned u; } v; v.f = f;
    unsigned u = v.u;
    unsigned r = (u + 0x7FFFu + ((u >> 16) & 1u)) >> 16;   // RNE
    return (ushort)r;
}

static __device__ __forceinline__ f32x4 fzero() {
    f32x4 v; v[0] = v[1] = v[2] = v[3] = 0.f; return v;
}

// ---------------------------------------------------------------------------
__global__ __launch_bounds__(256) void prep_w(const float* __restrict__ Wq,
                                              const float* __restrict__ Wk,
                                              const float* __restrict__ Wv,
                                              short* __restrict__ Wt) {
    const int c = blockIdx.x;      // 0..191
    const int t = threadIdx.x;     // 0..255
    const float* src; int cc; float sc = 1.0f;
    if (c < 64)       { src = Wq; cc = c;       sc = 0.125f; }
    else if (c < 128) { src = Wk; cc = c - 64;  }
    else              { src = Wv; cc = c - 128; }
    const int k0 = t * 4;
    s16x4 o;
    #pragma unroll
    for (int i = 0; i < 4; ++i) o[i] = (short)f2bf(src[(size_t)(k0 + i) * 64 + cc] * sc);
    *(s16x4*)&Wt[(size_t)c * 1024 + k0] = o;
}

// ---------------------------------------------------------------------------
__global__ __launch_bounds__(256) void proj(const float* __restrict__ x,
                                            const short* __restrict__ Wt,
                                            const float* __restrict__ bq,
                                            const float* __restrict__ bk,
                                            const float* __restrict__ bv,
                                            short* __restrict__ Qb,
                                            short* __restrict__ Kb,
                                            short* __restrict__ Vt) {
    const int tid  = threadIdx.x;
    const int lane = tid & 63;
    const int w    = tid >> 6;
    const int m0   = blockIdx.x * 32;
    const int l15  = lane & 15, gr = lane >> 4;

    __shared__ short xs[2][32][136];

    const int srow = tid >> 3;
    const int sc8  = tid & 7;
    const float* sbase = x + (size_t)(m0 + srow) * 1024 + 4 * sc8;

    f32x4 acc[3][2];
    #pragma unroll
    for (int m = 0; m < 3; ++m)
        for (int n = 0; n < 2; ++n) acc[m][n] = fzero();

    const short* aptr = Wt + (size_t)(48 * w + l15) * 1024 + 8 * gr;

    f32x4 ld[4];
    #pragma unroll
    for (int i = 0; i < 4; ++i) ld[i] = *(const f32x4*)(sbase + 32 * i);
    #pragma unroll
    for (int i = 0; i < 4; ++i) {
        s16x4 o;
        #pragma unroll
        for (int j = 0; j < 4; ++j) o[j] = (short)f2bf(ld[i][j]);
        *(s16x4*)&xs[0][srow][4 * sc8 + 32 * i] = o;
    }
    __syncthreads();

    for (int c = 0; c < 8; ++c) {
        const int buf = c & 1;
        if (c < 7) {
            #pragma unroll
            for (int i = 0; i < 4; ++i) ld[i] = *(const f32x4*)(sbase + 128 * (c + 1) + 32 * i);
        }
        #pragma unroll
        for (int f = 0; f < 4; ++f) {
            const int ko = 128 * c + 32 * f;
            s16x8 a[3];
            #pragma unroll
            for (int m = 0; m < 3; ++m) a[m] = *(const s16x8*)(aptr + (size_t)m * 16 * 1024 + ko);
            s16x8 b[2];
            #pragma unroll
            for (int n = 0; n < 2; ++n) b[n] = *(const s16x8*)&xs[buf][16 * n + l15][32 * f + 8 * gr];
            #pragma unroll
            for (int m = 0; m < 3; ++m)
                for (int n = 0; n < 2; ++n) acc[m][n] = MFMA16(a[m], b[n], acc[m][n]);
        }
        if (c < 7) {
            #pragma unroll
            for (int i = 0; i < 4; ++i) {
                s16x4 o;
                #pragma unroll
                for (int j = 0; j < 4; ++j) o[j] = (short)f2bf(ld[i][j]);
                *(s16x4*)&xs[buf ^ 1][srow][4 * sc8 + 32 * i] = o;
            }
        }
        __syncthreads();
    }

    #pragma unroll
    for (int m = 0; m < 3; ++m) {
        const int c0 = 48 * w + 16 * m + 4 * gr;
        #pragma unroll
        for (int n = 0; n < 2; ++n) {
            const int row = m0 + 16 * n + l15;
            f32x4 v = acc[m][n];
            if (c0 < 64) {
                s16x4 o;
                #pragma unroll
                for (int r = 0; r < 4; ++r) o[r] = (short)f2bf(v[r] + 0.125f * bq[c0 + r]);
                *(s16x4*)&Qb[(size_t)row * 64 + c0] = o;
            } else if (c0 < 128) {
                s16x4 o;
                #pragma unroll
                for (int r = 0; r < 4; ++r) o[r] = (short)f2bf(v[r] + bk[c0 - 64 + r]);
                *(s16x4*)&Kb[(size_t)row * 64 + (c0 - 64)] = o;
            } else {
                const int b = row >> 12, s = row & 4095;
                #pragma unroll
                for (int r = 0; r < 4; ++r)
                    Vt[((size_t)b * 64 + (c0 - 128 + r)) * 4096 + s] =
                        (short)f2bf(v[r] + bv[c0 - 128 + r]);
            }
        }
    }
}

// ---------------------------------------------------------------------------
__global__ __launch_bounds__(256, 2) void attn(const short* __restrict__ Qb,
                                               const short* __restrict__ Kb,
                                               const short* __restrict__ Vt,
                                               float* __restrict__ out) {
    const int bid   = blockIdx.x;
    const int wgid  = (bid & 7) * 64 + (bid >> 3);
    const int batch = wgid >> 7;
    const int g     = 127 - (wgid & 127);
    const int q0    = g * 32;
    const int tid   = threadIdx.x, lane = tid & 63, w = tid >> 6;
    const int l31   = lane & 31, h = lane >> 5, kb = 4 * h;

    __shared__ float Om[4][32][68];
    __shared__ float Mm[4][32], Lm[4][32];

    const size_t row0 = (size_t)batch * 4096;

    const short* Qp = Qb + (row0 + q0 + l31) * 64 + 8 * h;
    s16x8 qf[4];
    #pragma unroll
    for (int kk = 0; kk < 4; ++kk) qf[kk] = *(const s16x8*)(Qp + 16 * kk);

    f32x16 oT0, oT1;
    #pragma unroll
    for (int r = 0; r < 16; ++r) { oT0[r] = 0.f; oT1[r] = 0.f; }
    float m = -1e30f, l_ = 0.f;

    const int nt = g + 1;
    const int t0 = (nt * w) >> 2, t1 = (nt * (w + 1)) >> 2;

    const short* Kp = Kb + (row0 + l31) * 64 + 8 * h;
    const short* Vp = Vt + ((size_t)batch * 64 + l31) * 4096 + 8 * h;

    for (int t = t0; t < t1; ++t) {
        const int j0 = t * 32;
        s16x8 kf[4], va[2][2];
        #pragma unroll
        for (int kk = 0; kk < 4; ++kk)
            kf[kk] = *(const s16x8*)(Kp + (size_t)j0 * 64 + 16 * kk);
        #pragma unroll
        for (int dt = 0; dt < 2; ++dt)
            #pragma unroll
            for (int kk = 0; kk < 2; ++kk)
                va[dt][kk] = *(const s16x8*)(Vp + (size_t)dt * 32 * 4096 + j0 + 16 * kk);

        f32x16 sacc;
        #pragma unroll
        for (int r = 0; r < 16; ++r) sacc[r] = 0.f;
        #pragma unroll
        for (int kk = 0; kk < 4; ++kk) sacc = MFMA32(kf[kk], qf[kk], sacc);

        if (j0 == q0) {
            #pragma unroll
            for (int r = 0; r < 16; ++r) {
                const int kvloc = (r & 3) + 8 * (r >> 2) + kb;
                if (kvloc > l31) sacc[r] = -1e30f;
            }
        }

        float sm = sacc[0];
        #pragma unroll
        for (int r = 1; r < 16; ++r) sm = fmaxf(sm, sacc[r]);
        sm = fmaxf(sm, __shfl_xor(sm, 32));
        const float mn = fmaxf(m, sm);
        const float sc = __expf(m - mn);
        m = mn;

        float p[16]; float ls = 0.f;
        #pragma unroll
        for (int r = 0; r < 16; ++r) { p[r] = __expf(sacc[r] - mn); ls += p[r]; }
        l_ = l_ * sc + ls + __shfl_xor(ls, 32);
        #pragma unroll
        for (int r = 0; r < 16; ++r) { oT0[r] *= sc; oT1[r] *= sc; }

        unsigned pw[8];
        #pragma unroll
        for (int i = 0; i < 8; ++i)
            asm("v_cvt_pk_bf16_f32 %0, %1, %2" : "=v"(pw[i]) : "v"(p[2 * i]), "v"(p[2 * i + 1]));
        asm volatile("v_permlane32_swap_b32 %0, %1" : "+v"(pw[0]), "+v"(pw[2]));
        asm volatile("v_permlane32_swap_b32 %0, %1" : "+v"(pw[1]), "+v"(pw[3]));
        asm volatile("v_permlane32_swap_b32 %0, %1" : "+v"(pw[4]), "+v"(pw[6]));
        asm volatile("v_permlane32_swap_b32 %0, %1" : "+v"(pw[5]), "+v"(pw[7]));
        union { unsigned u[4]; s16x8 v; } f0, f1;
        f0.u[0] = pw[0]; f0.u[1] = pw[1]; f0.u[2] = pw[2]; f0.u[3] = pw[3];
        f1.u[0] = pw[4]; f1.u[1] = pw[5]; f1.u[2] = pw[6]; f1.u[3] = pw[7];

        oT0 = MFMA32(va[0][0], f0.v, oT0);
        oT0 = MFMA32(va[0][1], f1.v, oT0);
        oT1 = MFMA32(va[1][0], f0.v, oT1);
        oT1 = MFMA32(va[1][1], f1.v, oT1);
    }

    #pragma unroll
    for (int rg = 0; rg < 4; ++rg) {
        f32x4 v0, v1;
        #pragma unroll
        for (int j = 0; j < 4; ++j) { v0[j] = oT0[4 * rg + j]; v1[j] = oT1[4 * rg + j]; }
        const int d0 = rg * 8 + kb;
        *(f32x4*)&Om[w][l31][d0]      = v0;
        *(f32x4*)&Om[w][l31][32 + d0] = v1;
    }
    if (lane < 32) { Mm[w][l31] = m; Lm[w][l31] = l_; }
    __syncthreads();

    {
        const int q = tid >> 3, d0 = (tid & 7) * 8;
        const float m0 = Mm[0][q], m1 = Mm[1][q], m2 = Mm[2][q], m3 = Mm[3][q];
        const float mt = fmaxf(fmaxf(m0, m1), fmaxf(m2, m3));
        float sw[4];
        sw[0] = __expf(m0 - mt); sw[1] = __expf(m1 - mt);
        sw[2] = __expf(m2 - mt); sw[3] = __expf(m3 - mt);
        const float lt = sw[0] * Lm[0][q] + sw[1] * Lm[1][q] + sw[2] * Lm[2][q] + sw[3] * Lm[3][q];
        const float inv = 1.f / lt;
        f32x4 a0 = fzero(), a1 = fzero();
        #pragma unroll
        for (int ww = 0; ww < 4; ++ww) {
            f32x4 u0 = *(const f32x4*)&Om[ww][q][d0];
            f32x4 u1 = *(const f32x4*)&Om[ww][q][d0 + 4];
            #pragma unroll
            for (int j = 0; j < 4; ++j) { a0[j] += sw[ww] * u0[j]; a1[j] += sw[ww] * u1[j]; }
        }
        const size_t ob = (row0 + q0 + q) * 64 + d0;
        f32x4 r0, r1;
        #pragma unroll
        for (int j = 0; j < 4; ++j) { r0[j] = a0[j] * inv; r1[j] = a1[j] * inv; }
        *(f32x4*)&out[ob]     = r0;
        *(f32x4*)&out[ob + 4] = r1;
    }
}

// ---------------------------------------------------------------------------
extern "C" void kernel_launch(void* const* d_in, const int* in_sizes, int n_in,
                              void* d_out, int out_size, void* d_ws, size_t ws_size,
                              hipStream_t stream) {
    const float* x  = (const float*)d_in[0];
    const float* Wq = (const float*)d_in[2];
    const float* bq = (const float*)d_in[3];
    const float* Wk = (const float*)d_in[4];
    const float* bk = (const float*)d_in[5];
    const float* Wv = (const float*)d_in[6];
    const float* bv = (const float*)d_in[7];
    float* out = (float*)d_out;

    char* ws = (char*)d_ws;
    short* Wt = (short*)(ws);
    short* Qb = (short*)(ws + 393216);
    short* Kb = (short*)(ws + 2490368);
    short* Vt = (short*)(ws + 4587520);

    prep_w<<<dim3(192), dim3(256), 0, stream>>>(Wq, Wk, Wv, Wt);
    proj<<<dim3(512), dim3(256), 0, stream>>>(x, Wt, bq, bk, bv, Qb, Kb, Vt);
    // attn x8: idempotent (same inputs -> same out). attn_time = (T4 - T3)/7.
    for (int i = 0; i < 8; ++i)
        attn<<<dim3(512), dim3(256), 0, stream>>>(Qb, Kb, Vt, out);
}

// Round 5
// 85.306 us; speedup vs baseline: 5.3633x; 5.3633x over previous
//
#include <hip/hip_runtime.h>
#include <hip/hip_bf16.h>

// Self-attention head, B=4 S=4096 Dm=1024 Dk=64, fp32 in/out, bf16 MFMA inside.
// R5: latency-hiding round. attn: K/V register prefetch + XCD-batch affinity +
// tree reductions + defer-max(8). proj: A-prefetch + LDS pad 140. prep: coalesced.

typedef float  f32x4  __attribute__((ext_vector_type(4)));
typedef float  f32x16 __attribute__((ext_vector_type(16)));
typedef short  s16x8  __attribute__((ext_vector_type(8)));
typedef short  s16x4  __attribute__((ext_vector_type(4)));

#define MFMA16(A, B, C) __builtin_amdgcn_mfma_f32_16x16x32_bf16((A), (B), (C), 0, 0, 0)
#define MFMA32(A, B, C) __builtin_amdgcn_mfma_f32_32x32x16_bf16((A), (B), (C), 0, 0, 0)

static __device__ __forceinline__ ushort f2bf(float f) {
    union { float f; unsigned u; } v; v.f = f;
    unsigned u = v.u;
    unsigned r = (u + 0x7FFFu + ((u >> 16) & 1u)) >> 16;   // RNE
    return (ushort)r;
}

static __device__ __forceinline__ f32x4 fzero() {
    f32x4 v; v[0] = v[1] = v[2] = v[3] = 0.f; return v;
}

// ---------------------------------------------------------------------------
// prep_w (coalesced): 48 blocks = 3 mats x 16 k-tiles of 64. LDS transpose.
// Wt[c][k], c in [0,192): 0..63 Q (x0.125 folded), 64..127 K, 128..191 V.
// ---------------------------------------------------------------------------
__global__ __launch_bounds__(256) void prep_w(const float* __restrict__ Wq,
                                              const float* __restrict__ Wk,
                                              const float* __restrict__ Wv,
                                              short* __restrict__ Wt) {
    const int blk = blockIdx.x;              // 0..47
    const int mat = blk >> 4, kt = blk & 15;
    const float* src = mat == 0 ? Wq : (mat == 1 ? Wk : Wv);
    const float sc = (mat == 0) ? 0.125f : 1.0f;
    __shared__ float wsm[64][68];
    const int t = threadIdx.x;

    // load 64 k-rows x 64 c-cols, coalesced: 4 rows dense per instruction
    const int rb = t >> 4, c4 = (t & 15) * 4;
    #pragma unroll
    for (int i = 0; i < 4; ++i) {
        f32x4 v = *(const f32x4*)&src[(size_t)(kt * 64 + rb + 16 * i) * 64 + c4];
        *(f32x4*)&wsm[rb + 16 * i][c4] = v;
    }
    __syncthreads();

    // write out transposed: thread -> (c = t>>2, k-seg of 16)
    const int c = t >> 2, ks = (t & 3) * 16;
    s16x8 o0, o1;
    #pragma unroll
    for (int j = 0; j < 8; ++j) o0[j] = (short)f2bf(wsm[ks + j][c] * sc);
    #pragma unroll
    for (int j = 0; j < 8; ++j) o1[j] = (short)f2bf(wsm[ks + 8 + j][c] * sc);
    const size_t ob = (size_t)(mat * 64 + c) * 1024 + kt * 64 + ks;
    *(s16x8*)&Wt[ob]     = o0;
    *(s16x8*)&Wt[ob + 8] = o1;
}

// ---------------------------------------------------------------------------
// proj: out^T = Wt(192x1024) @ x^T(1024x32-per-block). 4 waves, LDS dbuf,
// A-fragment register prefetch one f-iter ahead.
// ---------------------------------------------------------------------------
__global__ __launch_bounds__(256) void proj(const float* __restrict__ x,
                                            const short* __restrict__ Wt,
                                            const float* __restrict__ bq,
                                            const float* __restrict__ bk,
                                            const float* __restrict__ bv,
                                            short* __restrict__ Qb,
                                            short* __restrict__ Kb,
                                            short* __restrict__ Vt) {
    const int tid  = threadIdx.x;
    const int lane = tid & 63;
    const int w    = tid >> 6;
    const int m0   = blockIdx.x * 32;
    const int l15  = lane & 15, gr = lane >> 4;

    __shared__ short xs[2][32][140];         // pad 140 -> ~2-way banks on b128

    const int srow = tid >> 3;
    const int sc8  = tid & 7;
    const float* sbase = x + (size_t)(m0 + srow) * 1024 + 4 * sc8;

    f32x4 acc[3][2];
    #pragma unroll
    for (int m = 0; m < 3; ++m)
        for (int n = 0; n < 2; ++n) acc[m][n] = fzero();

    const short* aptr = Wt + (size_t)(48 * w + l15) * 1024 + 8 * gr;

    f32x4 ld[4];
    #pragma unroll
    for (int i = 0; i < 4; ++i) ld[i] = *(const f32x4*)(sbase + 32 * i);
    #pragma unroll
    for (int i = 0; i < 4; ++i) {
        s16x4 o;
        #pragma unroll
        for (int j = 0; j < 4; ++j) o[j] = (short)f2bf(ld[i][j]);
        *(s16x4*)&xs[0][srow][4 * sc8 + 32 * i] = o;
    }

    s16x8 a_cur[3], a_nxt[3];
    #pragma unroll
    for (int m = 0; m < 3; ++m) a_cur[m] = *(const s16x8*)(aptr + (size_t)m * 16 * 1024);
    __syncthreads();

    for (int c = 0; c < 8; ++c) {
        const int buf = c & 1;
        if (c < 7) {
            #pragma unroll
            for (int i = 0; i < 4; ++i) ld[i] = *(const f32x4*)(sbase + 128 * (c + 1) + 32 * i);
        }
        #pragma unroll
        for (int f = 0; f < 4; ++f) {
            const int ko = 128 * c + 32 * f;
            const int kn = (ko + 32) & 1023;          // wraps to 0 on last iter (dead)
            #pragma unroll
            for (int m = 0; m < 3; ++m) a_nxt[m] = *(const s16x8*)(aptr + (size_t)m * 16 * 1024 + kn);
            s16x8 b[2];
            #pragma unroll
            for (int n = 0; n < 2; ++n) b[n] = *(const s16x8*)&xs[buf][16 * n + l15][32 * f + 8 * gr];
            #pragma unroll
            for (int m = 0; m < 3; ++m)
                for (int n = 0; n < 2; ++n) acc[m][n] = MFMA16(a_cur[m], b[n], acc[m][n]);
            #pragma unroll
            for (int m = 0; m < 3; ++m) a_cur[m] = a_nxt[m];
        }
        if (c < 7) {
            #pragma unroll
            for (int i = 0; i < 4; ++i) {
                s16x4 o;
                #pragma unroll
                for (int j = 0; j < 4; ++j) o[j] = (short)f2bf(ld[i][j]);
                *(s16x4*)&xs[buf ^ 1][srow][4 * sc8 + 32 * i] = o;
            }
        }
        __syncthreads();
    }

    #pragma unroll
    for (int m = 0; m < 3; ++m) {
        const int c0 = 48 * w + 16 * m + 4 * gr;
        #pragma unroll
        for (int n = 0; n < 2; ++n) {
            const int row = m0 + 16 * n + l15;
            f32x4 v = acc[m][n];
            if (c0 < 64) {
                s16x4 o;
                #pragma unroll
                for (int r = 0; r < 4; ++r) o[r] = (short)f2bf(v[r] + 0.125f * bq[c0 + r]);
                *(s16x4*)&Qb[(size_t)row * 64 + c0] = o;
            } else if (c0 < 128) {
                s16x4 o;
                #pragma unroll
                for (int r = 0; r < 4; ++r) o[r] = (short)f2bf(v[r] + bk[c0 - 64 + r]);
                *(s16x4*)&Kb[(size_t)row * 64 + (c0 - 64)] = o;
            } else {
                const int b = row >> 12, s = row & 4095;
                #pragma unroll
                for (int r = 0; r < 4; ++r)
                    Vt[((size_t)b * 64 + (c0 - 128 + r)) * 4096 + s] =
                        (short)f2bf(v[r] + bv[c0 - 128 + r]);
            }
        }
    }
}

// ---------------------------------------------------------------------------
// attn: 32x32 swapped-operand S^T, in-register softmax, K/V register prefetch,
// defer-max(8), XCD-batch affinity (each XCD pair owns one batch -> K/V L2-fit).
// ---------------------------------------------------------------------------
__global__ __launch_bounds__(256, 2) void attn(const short* __restrict__ Qb,
                                               const short* __restrict__ Kb,
                                               const short* __restrict__ Vt,
                                               float* __restrict__ out) {
    const int bid   = blockIdx.x;                 // 512
    const int xcd   = bid & 7, bi = bid >> 3;     // presumed XCD round-robin
    const int batch = xcd >> 1;                   // one batch per XCD pair
    const int g     = 127 - 2 * bi - (xcd & 1);   // heavy-first, bijective
    const int q0    = g * 32;
    const int tid   = threadIdx.x, lane = tid & 63, w = tid >> 6;
    const int l31   = lane & 31, h = lane >> 5, kb = 4 * h;

    __shared__ float Om[4][32][68];
    __shared__ float Mm[4][32], Lm[4][32];

    const size_t row0 = (size_t)batch * 4096;

    const short* Qp = Qb + (row0 + q0 + l31) * 64 + 8 * h;
    s16x8 qf[4];
    #pragma unroll
    for (int kk = 0; kk < 4; ++kk) qf[kk] = *(const s16x8*)(Qp + 16 * kk);

    f32x16 oT0, oT1;
    #pragma unroll
    for (int r = 0; r < 16; ++r) { oT0[r] = 0.f; oT1[r] = 0.f; }
    float m = -1e30f, l_ = 0.f;

    const int nt = g + 1;
    const int t0 = (nt * w) >> 2, t1 = (nt * (w + 1)) >> 2;

    const short* Kp = Kb + (row0 + l31) * 64 + 8 * h;
    const short* Vp = Vt + ((size_t)batch * 64 + l31) * 4096 + 8 * h;

    s16x8 kf[4], va[2][2], kf2[4], va2[2][2];
    if (t0 < t1) {
        const int j0 = t0 * 32;
        #pragma unroll
        for (int kk = 0; kk < 4; ++kk) kf[kk] = *(const s16x8*)(Kp + (size_t)j0 * 64 + 16 * kk);
        #pragma unroll
        for (int dt = 0; dt < 2; ++dt)
            #pragma unroll
            for (int kk = 0; kk < 2; ++kk)
                va[dt][kk] = *(const s16x8*)(Vp + (size_t)dt * 32 * 4096 + j0 + 16 * kk);
    }

    for (int t = t0; t < t1; ++t) {
        const int j0 = t * 32;
        if (t + 1 < t1) {                          // prefetch next tile
            const int jn = j0 + 32;
            #pragma unroll
            for (int kk = 0; kk < 4; ++kk) kf2[kk] = *(const s16x8*)(Kp + (size_t)jn * 64 + 16 * kk);
            #pragma unroll
            for (int dt = 0; dt < 2; ++dt)
                #pragma unroll
                for (int kk = 0; kk < 2; ++kk)
                    va2[dt][kk] = *(const s16x8*)(Vp + (size_t)dt * 32 * 4096 + jn + 16 * kk);
        }

        f32x16 sacc;
        #pragma unroll
        for (int r = 0; r < 16; ++r) sacc[r] = 0.f;
        #pragma unroll
        for (int kk = 0; kk < 4; ++kk) sacc = MFMA32(kf[kk], qf[kk], sacc);

        if (j0 == q0) {                            // diagonal tile: mask kv > q
            #pragma unroll
            for (int r = 0; r < 16; ++r) {
                const int kvloc = (r & 3) + 8 * (r >> 2) + kb;
                if (kvloc > l31) sacc[r] = -1e30f;
            }
        }

        // tree row-max (depth 4) + cross-half
        float tm[8];
        #pragma unroll
        for (int r = 0; r < 8; ++r) tm[r] = fmaxf(sacc[r], sacc[r + 8]);
        #pragma unroll
        for (int r = 0; r < 4; ++r) tm[r] = fmaxf(tm[r], tm[r + 4]);
        tm[0] = fmaxf(fmaxf(tm[0], tm[2]), fmaxf(tm[1], tm[3]));
        float sm = fmaxf(tm[0], __shfl_xor(tm[0], 32));

        if (!__all(sm - m <= 8.f)) {               // defer-max: rescale only on growth
            const float mn = fmaxf(m, sm);
            const float sc = __expf(m - mn);
            m = mn;
            l_ *= sc;
            #pragma unroll
            for (int r = 0; r < 16; ++r) { oT0[r] *= sc; oT1[r] *= sc; }
        }

        float p[16];
        #pragma unroll
        for (int r = 0; r < 16; ++r) p[r] = __expf(sacc[r] - m);
        float ts[8];
        #pragma unroll
        for (int r = 0; r < 8; ++r) ts[r] = p[r] + p[r + 8];
        #pragma unroll
        for (int r = 0; r < 4; ++r) ts[r] = ts[r] + ts[r + 4];
        const float ls = (ts[0] + ts[2]) + (ts[1] + ts[3]);
        l_ += ls + __shfl_xor(ls, 32);

        unsigned pw[8];
        #pragma unroll
        for (int i = 0; i < 8; ++i)
            asm("v_cvt_pk_bf16_f32 %0, %1, %2" : "=v"(pw[i]) : "v"(p[2 * i]), "v"(p[2 * i + 1]));
        asm volatile("v_permlane32_swap_b32 %0, %1" : "+v"(pw[0]), "+v"(pw[2]));
        asm volatile("v_permlane32_swap_b32 %0, %1" : "+v"(pw[1]), "+v"(pw[3]));
        asm volatile("v_permlane32_swap_b32 %0, %1" : "+v"(pw[4]), "+v"(pw[6]));
        asm volatile("v_permlane32_swap_b32 %0, %1" : "+v"(pw[5]), "+v"(pw[7]));
        union { unsigned u[4]; s16x8 v; } f0, f1;
        f0.u[0] = pw[0]; f0.u[1] = pw[1]; f0.u[2] = pw[2]; f0.u[3] = pw[3];
        f1.u[0] = pw[4]; f1.u[1] = pw[5]; f1.u[2] = pw[6]; f1.u[3] = pw[7];

        oT0 = MFMA32(va[0][0], f0.v, oT0);
        oT0 = MFMA32(va[0][1], f1.v, oT0);
        oT1 = MFMA32(va[1][0], f0.v, oT1);
        oT1 = MFMA32(va[1][1], f1.v, oT1);

        #pragma unroll
        for (int kk = 0; kk < 4; ++kk) kf[kk] = kf2[kk];
        #pragma unroll
        for (int dt = 0; dt < 2; ++dt)
            #pragma unroll
            for (int kk = 0; kk < 2; ++kk) va[dt][kk] = va2[dt][kk];
    }

    #pragma unroll
    for (int rg = 0; rg < 4; ++rg) {
        f32x4 v0, v1;
        #pragma unroll
        for (int j = 0; j < 4; ++j) { v0[j] = oT0[4 * rg + j]; v1[j] = oT1[4 * rg + j]; }
        const int d0 = rg * 8 + kb;
        *(f32x4*)&Om[w][l31][d0]      = v0;
        *(f32x4*)&Om[w][l31][32 + d0] = v1;
    }
    if (lane < 32) { Mm[w][l31] = m; Lm[w][l31] = l_; }
    __syncthreads();

    {
        const int q = tid >> 3, d0 = (tid & 7) * 8;
        const float m0 = Mm[0][q], m1 = Mm[1][q], m2 = Mm[2][q], m3 = Mm[3][q];
        const float mt = fmaxf(fmaxf(m0, m1), fmaxf(m2, m3));
        float sw[4];
        sw[0] = __expf(m0 - mt); sw[1] = __expf(m1 - mt);
        sw[2] = __expf(m2 - mt); sw[3] = __expf(m3 - mt);
        const float lt = sw[0] * Lm[0][q] + sw[1] * Lm[1][q] + sw[2] * Lm[2][q] + sw[3] * Lm[3][q];
        const float inv = 1.f / lt;
        f32x4 a0 = fzero(), a1 = fzero();
        #pragma unroll
        for (int ww = 0; ww < 4; ++ww) {
            f32x4 u0 = *(const f32x4*)&Om[ww][q][d0];
            f32x4 u1 = *(const f32x4*)&Om[ww][q][d0 + 4];
            #pragma unroll
            for (int j = 0; j < 4; ++j) { a0[j] += sw[ww] * u0[j]; a1[j] += sw[ww] * u1[j]; }
        }
        const size_t ob = (row0 + q0 + q) * 64 + d0;
        f32x4 r0, r1;
        #pragma unroll
        for (int j = 0; j < 4; ++j) { r0[j] = a0[j] * inv; r1[j] = a1[j] * inv; }
        *(f32x4*)&out[ob]     = r0;
        *(f32x4*)&out[ob + 4] = r1;
    }
}

// ---------------------------------------------------------------------------
extern "C" void kernel_launch(void* const* d_in, const int* in_sizes, int n_in,
                              void* d_out, int out_size, void* d_ws, size_t ws_size,
                              hipStream_t stream) {
    const float* x  = (const float*)d_in[0];
    const float* Wq = (const float*)d_in[2];
    const float* bq = (const float*)d_in[3];
    const float* Wk = (const float*)d_in[4];
    const float* bk = (const float*)d_in[5];
    const float* Wv = (const float*)d_in[6];
    const float* bv = (const float*)d_in[7];
    float* out = (float*)d_out;

    char* ws = (char*)d_ws;
    short* Wt = (short*)(ws);
    short* Qb = (short*)(ws + 393216);
    short* Kb = (short*)(ws + 2490368);
    short* Vt = (short*)(ws + 4587520);

    prep_w<<<dim3(48), dim3(256), 0, stream>>>(Wq, Wk, Wv, Wt);
    proj<<<dim3(512), dim3(256), 0, stream>>>(x, Wt, bq, bk, bv, Qb, Kb, Vt);
    attn<<<dim3(512), dim3(256), 0, stream>>>(Qb, Kb, Vt, out);
}